// Round 1
// baseline (99.392 us; speedup 1.0000x reference)
//
#include <hip/hip_runtime.h>
#include <math.h>

#define NEGS 20
#define DIMS 128
#define REGC 1e-6f

__device__ __forceinline__ float log_sigmoid(float x) {
    // stable: logsig(x) = min(x,0) - log1p(exp(-|x|))
    float ax = fabsf(x);
    float l = -log1pf(__expf(-ax));
    return x >= 0.f ? l : x + l;
}

__global__ __launch_bounds__(256) void sg_loss_kernel(
    const float* __restrict__ u_emb,
    const float* __restrict__ v_emb,
    const float* __restrict__ pretrained,
    const int* __restrict__ u_pos,
    const int* __restrict__ v_pos,
    const int* __restrict__ v_neg,
    float* __restrict__ out,
    int batch)
{
    const int lane = threadIdx.x & 63;
    const int wib  = threadIdx.x >> 6;          // wave in block
    const int wpb  = blockDim.x >> 6;           // waves per block
    const int gwave  = blockIdx.x * wpb + wib;
    const int nwaves = gridDim.x * wpb;

    float s1 = 0.f;   // sum of (log_target + sum_log_sampled), full value per wave
    float s2 = 0.f;   // sum |u - pretrained|

    for (int b = gwave; b < batch; b += nwaves) {
        const int iu = u_pos[b];
        const int iv = v_pos[b];

        // preload neg indices so all row loads below can be issued together
        int negidx[NEGS];
        #pragma unroll
        for (int n = 0; n < NEGS; ++n) negidx[n] = v_neg[b * NEGS + n];

        // lane holds dims {2*lane, 2*lane+1}: 64 lanes x 8B = 512B coalesced row
        const float2 u = *((const float2*)(u_emb      + (size_t)iu * DIMS) + lane);
        const float2 v = *((const float2*)(v_emb      + (size_t)iv * DIMS) + lane);
        const float2 p = *((const float2*)(pretrained + (size_t)iu * DIMS) + lane);

        float part[NEGS + 1];
        part[0] = u.x * v.x + u.y * v.y;
        #pragma unroll
        for (int n = 0; n < NEGS; ++n) {
            const float2 nv = *((const float2*)(v_emb + (size_t)negidx[n] * DIMS) + lane);
            part[n + 1] = u.x * nv.x + u.y * nv.y;
        }
        float rp = fabsf(u.x - p.x) + fabsf(u.y - p.y);

        // one 64-lane butterfly over all 22 partials; all lanes end with full sums
        #pragma unroll
        for (int off = 32; off > 0; off >>= 1) {
            #pragma unroll
            for (int k = 0; k <= NEGS; ++k) part[k] += __shfl_xor(part[k], off, 64);
            rp += __shfl_xor(rp, off, 64);
        }

        // wave-uniform nonlinearity (redundant across lanes, but no divergence)
        float acc = log_sigmoid(part[0]);
        #pragma unroll
        for (int n = 0; n < NEGS; ++n) acc += log_sigmoid(-part[n + 1]);
        s1 += acc;
        s2 += rp;
    }

    // block reduce (values are wave-uniform; lane 0 of each wave contributes)
    __shared__ float ls1[8], ls2[8];
    if (lane == 0) { ls1[wib] = s1; ls2[wib] = s2; }
    __syncthreads();
    if (threadIdx.x == 0) {
        float t1 = 0.f, t2 = 0.f;
        for (int w = 0; w < wpb; ++w) { t1 += ls1[w]; t2 += ls2[w]; }
        // out = -(S1)/B - REG*S2   (reg_total broadcast over B cancels the /B)
        const float contrib = -(t1 / (float)batch) - REGC * t2;
        atomicAdd(out, contrib);
    }
}

extern "C" void kernel_launch(void* const* d_in, const int* in_sizes, int n_in,
                              void* d_out, int out_size, void* d_ws, size_t ws_size,
                              hipStream_t stream) {
    const float* u_emb      = (const float*)d_in[0];
    const float* v_emb      = (const float*)d_in[1];
    const float* pretrained = (const float*)d_in[2];
    const int*   u_pos      = (const int*)d_in[3];
    const int*   v_pos      = (const int*)d_in[4];
    const int*   v_neg      = (const int*)d_in[5];
    float* out = (float*)d_out;
    const int batch = in_sizes[3];

    // d_out is poisoned once before timing and never re-poisoned: zero it ourselves
    hipMemsetAsync(out, 0, sizeof(float), stream);

    dim3 block(256);
    dim3 grid(2048);   // 8192 waves, grid-stride: 2 batch rows per wave
    sg_loss_kernel<<<grid, block, 0, stream>>>(u_emb, v_emb, pretrained,
                                               u_pos, v_pos, v_neg, out, batch);
}

// Round 2
// 46.811 us; speedup vs baseline: 2.1233x; 2.1233x over previous
//
#include <hip/hip_runtime.h>
#include <math.h>

#define NEGS 20
#define DIMS 128
#define REGC 1e-6f
#define LPR  16            // lanes per row
#define RPW  4             // rows per wave = 64/LPR

__device__ __forceinline__ float log_sigmoid(float x) {
    // stable: logsig(x) = min(x,0) - log(1+exp(-|x|)); fast exp/log (args tiny here)
    float t = __expf(-fabsf(x));
    float l = -__logf(1.f + t);
    return x >= 0.f ? l : x + l;
}

__device__ __forceinline__ float dot4(float4 a, float4 b) {
    return a.x*b.x + a.y*b.y + a.z*b.z + a.w*b.w;
}

__global__ __launch_bounds__(256) void sg_loss_kernel(
    const float* __restrict__ u_emb,
    const float* __restrict__ v_emb,
    const float* __restrict__ pretrained,
    const int* __restrict__ u_pos,
    const int* __restrict__ v_pos,
    const int* __restrict__ v_neg,
    float* __restrict__ out,
    int batch)
{
    const int lane = threadIdx.x & 63;
    const int l    = lane & (LPR - 1);     // lane within 16-lane row group
    const int g    = lane >> 4;            // row group within wave (0..3)
    const int wib  = threadIdx.x >> 6;
    const int wpb  = blockDim.x >> 6;
    const int gwave  = blockIdx.x * wpb + wib;
    const int nwaves = gridDim.x * wpb;

    float s1 = 0.f;   // sum of (log_target + sum_log_sampled)
    float s2 = 0.f;   // sum |u - pretrained|

    for (int base = gwave * RPW; base < batch; base += nwaves * RPW) {
        const int  b     = base + g;
        const bool valid = (b < batch);
        const int  ib    = valid ? b : 0;

        const int iu = u_pos[ib];
        const int iv = v_pos[ib];

        int negidx[NEGS];
        #pragma unroll
        for (int n = 0; n < NEGS; ++n) negidx[n] = v_neg[ib * NEGS + n];

        // lane l covers float4 chunks {l, l+16}: 16 lanes x 16B = 256B contiguous
        const float4* up = (const float4*)(u_emb      + (size_t)iu * DIMS);
        const float4* vp = (const float4*)(v_emb      + (size_t)iv * DIMS);
        const float4* pp = (const float4*)(pretrained + (size_t)iu * DIMS);
        const float4 u0 = up[l], u1 = up[l + 16];
        const float4 v0 = vp[l], v1 = vp[l + 16];
        const float4 p0 = pp[l], p1 = pp[l + 16];

        float part[NEGS + 1];
        part[0] = dot4(u0, v0) + dot4(u1, v1);
        #pragma unroll
        for (int n = 0; n < NEGS; ++n) {
            const float4* np = (const float4*)(v_emb + (size_t)negidx[n] * DIMS);
            const float4 a = np[l], c = np[l + 16];
            part[n + 1] = dot4(u0, a) + dot4(u1, c);
        }
        float rp = fabsf(u0.x - p0.x) + fabsf(u0.y - p0.y)
                 + fabsf(u0.z - p0.z) + fabsf(u0.w - p0.w)
                 + fabsf(u1.x - p1.x) + fabsf(u1.y - p1.y)
                 + fabsf(u1.z - p1.z) + fabsf(u1.w - p1.w);

        // 4-stage butterfly within each 16-lane group; amortized over 4 rows/wave
        #pragma unroll
        for (int off = 8; off > 0; off >>= 1) {
            #pragma unroll
            for (int k = 0; k <= NEGS; ++k) part[k] += __shfl_xor(part[k], off, 16);
            rp += __shfl_xor(rp, off, 16);
        }

        // group-uniform nonlinearity: 1 wave instr covers 4 rows
        float acc = log_sigmoid(part[0]);
        #pragma unroll
        for (int n = 0; n < NEGS; ++n) acc += log_sigmoid(-part[n + 1]);

        if (!valid) { acc = 0.f; rp = 0.f; }
        s1 += acc;
        s2 += rp;
    }

    // combine the 4 groups within the wave (s1/s2 group-uniform)
    s1 += __shfl_xor(s1, 16, 64);  s2 += __shfl_xor(s2, 16, 64);
    s1 += __shfl_xor(s1, 32, 64);  s2 += __shfl_xor(s2, 32, 64);

    __shared__ float ls1[8], ls2[8];
    if (lane == 0) { ls1[wib] = s1; ls2[wib] = s2; }
    __syncthreads();
    if (threadIdx.x == 0) {
        float t1 = 0.f, t2 = 0.f;
        for (int w = 0; w < wpb; ++w) { t1 += ls1[w]; t2 += ls2[w]; }
        // out = -(S1)/B - REG*S2   (reg_total broadcast over B cancels the /B)
        const float contrib = -(t1 / (float)batch) - REGC * t2;
        atomicAdd(out, contrib);
    }
}

extern "C" void kernel_launch(void* const* d_in, const int* in_sizes, int n_in,
                              void* d_out, int out_size, void* d_ws, size_t ws_size,
                              hipStream_t stream) {
    const float* u_emb      = (const float*)d_in[0];
    const float* v_emb      = (const float*)d_in[1];
    const float* pretrained = (const float*)d_in[2];
    const int*   u_pos      = (const int*)d_in[3];
    const int*   v_pos      = (const int*)d_in[4];
    const int*   v_neg      = (const int*)d_in[5];
    float* out = (float*)d_out;
    const int batch = in_sizes[3];

    hipMemsetAsync(out, 0, sizeof(float), stream);

    dim3 block(256);
    // one wave handles RPW rows in a single pass: waves = ceil(batch/RPW)
    int nwaves = (batch + RPW - 1) / RPW;          // 4096 for B=16384
    int blocks = (nwaves + 3) / 4;                 // 4 waves per block -> 1024
    sg_loss_kernel<<<dim3(blocks), block, 0, stream>>>(u_emb, v_emb, pretrained,
                                                       u_pos, v_pos, v_neg, out, batch);
}